// Round 2
// baseline (1853.763 us; speedup 1.0000x reference)
//
#include <hip/hip_runtime.h>
#include <cstdint>

#ifndef JAX_PARTITIONABLE
#define JAX_PARTITIONABLE 1   // modern JAX (>=0.5) default threefry_partitionable
#endif

// ---------------- Threefry-2x32, key = (0, 42)  (jax.random.key(42)) ----------------
__device__ __forceinline__ uint32_t rotl32(uint32_t v, int s){ return (v << s) | (v >> (32 - s)); }

__device__ __forceinline__ void tf2x32(uint32_t& x0, uint32_t& x1){
  const uint32_t k0 = 0u, k1 = 42u;
  const uint32_t k2 = 0x1BD11BDAu ^ k0 ^ k1;
  x0 += k0; x1 += k1;
#define TFR(r) { x0 += x1; x1 = rotl32(x1,(r)); x1 ^= x0; }
  TFR(13) TFR(15) TFR(26) TFR(6)
  x0 += k1; x1 += k2 + 1u;
  TFR(17) TFR(29) TFR(16) TFR(24)
  x0 += k2; x1 += k0 + 2u;
  TFR(13) TFR(15) TFR(26) TFR(6)
  x0 += k0; x1 += k1 + 3u;
  TFR(17) TFR(29) TFR(16) TFR(24)
  x0 += k1; x1 += k2 + 4u;
  TFR(13) TFR(15) TFR(26) TFR(6)
  x0 += k2; x1 += k0 + 5u;
#undef TFR
}

// XLA f32 ErfInv (Giles) — exact coefficient match with jax/XLA
__device__ __forceinline__ float erfinv_xla(float x){
  float w = -log1pf(-x*x);
  float p;
  if (w < 5.0f){
    w -= 2.5f;
    p =  2.81022636e-08f;
    p = fmaf(p,w, 3.43273939e-07f);
    p = fmaf(p,w,-3.5233877e-06f);
    p = fmaf(p,w,-4.39150654e-06f);
    p = fmaf(p,w, 0.00021858087f);
    p = fmaf(p,w,-0.00125372503f);
    p = fmaf(p,w,-0.00417768164f);
    p = fmaf(p,w, 0.246640727f);
    p = fmaf(p,w, 1.50140941f);
  } else {
    w = sqrtf(w) - 3.0f;
    p = -0.000200214257f;
    p = fmaf(p,w, 0.000100950558f);
    p = fmaf(p,w, 0.00134934322f);
    p = fmaf(p,w,-0.00367342844f);
    p = fmaf(p,w, 0.00573950773f);
    p = fmaf(p,w,-0.0076224613f);
    p = fmaf(p,w, 0.00943887047f);
    p = fmaf(p,w, 1.00167406f);
    p = fmaf(p,w, 2.83297682f);
  }
  return p*x;
}

// noise[i] = 0.8 * sqrt(2)*erfinv(uniform(-1,1)) with jax bit semantics
__device__ __forceinline__ float noise_at(uint32_t idx, uint32_t half){
#if JAX_PARTITIONABLE
  (void)half;
  uint32_t x0 = 0u, x1 = idx;     // counter = (hi=0, lo=i)
  tf2x32(x0, x1);
  uint32_t bits = x0 ^ x1;        // partitionable 32-bit path: xor-fold of both words
#else
  uint32_t j  = (idx < half) ? idx : (idx - half);
  uint32_t x0 = j, x1 = j + half;
  tf2x32(x0, x1);
  uint32_t bits = (idx < half) ? x0 : x1;
#endif
  float f = __uint_as_float((bits >> 9) | 0x3f800000u) - 1.0f;      // [0,1)
  float u = fmaxf(-0.99999994f, fmaf(f, 2.0f, -0.99999994f));       // (-1,1)
  return (1.41421356f * erfinv_xla(u)) * 0.8f;
}

// jax.nn.gelu approximate=True
__device__ __forceinline__ float tanh_fast(float x){
  float e = __expf(2.0f * x);
  return 1.0f - 2.0f * __builtin_amdgcn_rcpf(e + 1.0f);
}
__device__ __forceinline__ float gelu_f(float x){
  float inner = 0.7978845608028654f * (x + 0.044715f*(x*x*x));
  return 0.5f * x * (1.0f + tanh_fast(inner));
}

// ---------------- P2G scatter: 7 channels into 128^3 grid (stride 8 floats) ----------------
__global__ void __launch_bounds__(256) p2g_kernel(
    const float* __restrict__ xsr, const float* __restrict__ xsc,
    const float* __restrict__ Wf,  const float* __restrict__ bf,
    float* __restrict__ grid, int N)
{
  int i = blockIdx.x*256 + threadIdx.x;
  if (i >= N) return;
  float sx = fminf(fmaxf(xsr[3*i+0], 0.0f), 1.0f);
  float sy = fminf(fmaxf(xsr[3*i+1], 0.0f), 1.0f);
  float sz = fminf(fmaxf(xsr[3*i+2], 0.0f), 1.0f);
  float ux = xsc[3*i+0] - sx;
  float uy = xsc[3*i+1] - sy;
  float uz = xsc[3*i+2] - sz;
  float f0 = gelu_f(ux*Wf[0] + uy*Wf[3] + uz*Wf[6] + bf[0]);
  float f1 = gelu_f(ux*Wf[1] + uy*Wf[4] + uz*Wf[7] + bf[1]);
  float f2 = gelu_f(ux*Wf[2] + uy*Wf[5] + uz*Wf[8] + bf[2]);

  float cx = fminf(fmaxf(sx*127.0f, 0.0f), 126.999f);
  float cy = fminf(fmaxf(sy*127.0f, 0.0f), 126.999f);
  float cz = fminf(fmaxf(sz*127.0f, 0.0f), 126.999f);
  float bxf = floorf(cx), byf = floorf(cy), bzf = floorf(cz);
  int bx = (int)bxf, by = (int)byf, bz = (int)bzf;
  float dx = cx - bxf, dy = cy - byf, dz = cz - bzf;
  float ex = 1.0f - dx, ey = 1.0f - dy, ez = 1.0f - dz;

  auto splat = [&](int xi, int yi, int zi, float w){
    float* p = grid + ((size_t)((((xi<<7)+yi)<<7)+zi) << 3);
    unsafeAtomicAdd(p+0, f0*w);
    unsafeAtomicAdd(p+1, f1*w);
    unsafeAtomicAdd(p+2, f2*w);
    unsafeAtomicAdd(p+3, w);
    unsafeAtomicAdd(p+4, ux*w);
    unsafeAtomicAdd(p+5, uy*w);
    unsafeAtomicAdd(p+6, uz*w);
  };
  splat(bx,  by,  bz,   ex*ey*ez);
  splat(bx,  by,  bz+1, ex*ey*dz);
  splat(bx,  by+1,bz,   ex*dy*ez);
  splat(bx,  by+1,bz+1, ex*dy*dz);
  splat(bx+1,by,  bz,   dx*ey*ez);
  splat(bx+1,by,  bz+1, dx*ey*dz);
  splat(bx+1,by+1,bz,   dx*dy*ez);
  splat(bx+1,by+1,bz+1, dx*dy*dz);
}

// ---------------- gather (8 MC paths, trilerp) + normalize + posenc + MLP ----------------
__global__ void __launch_bounds__(64) gather_mlp_kernel(
    const float* __restrict__ xq,  const float* __restrict__ grid,
    const float* __restrict__ W1,  const float* __restrict__ b1,
    const float* __restrict__ W2,  const float* __restrict__ b2,
    const float* __restrict__ W3,  const float* __restrict__ b3,
    float* __restrict__ out, int M)
{
  __shared__ float sh[64*33];              // per-thread 33-float row; (t*33+k)%32=(t+k)%32 -> conflict-free
  int m = blockIdx.x*64 + threadIdx.x;
  if (m >= M) return;
  float* row = sh + threadIdx.x*33;

  float qx01 = fminf(fmaxf(xq[3*m+0], 0.0f), 1.0f);
  float qy01 = fminf(fmaxf(xq[3*m+1], 0.0f), 1.0f);
  float qz01 = fminf(fmaxf(xq[3*m+2], 0.0f), 1.0f);
  float qx = qx01*127.0f, qy = qy01*127.0f, qz = qz01*127.0f;

  float r0=0.f,r1=0.f,r2=0.f,r3=0.f,r4=0.f,r5=0.f,r6=0.f;
  const uint32_t KSTRIDE = 3u*(uint32_t)M;       // 1,500,000
  const uint32_t HALF    = 4u*KSTRIDE;           // 6,000,000 (legacy scheme only)
  uint32_t m3 = 3u*(uint32_t)m;

  for (int k = 0; k < 8; ++k) {
    uint32_t base = (uint32_t)k*KSTRIDE + m3;    // flat idx into (8,M,3)
    float px = qx + noise_at(base+0u, HALF);
    float py = qy + noise_at(base+1u, HALF);
    float pz = qz + noise_at(base+2u, HALF);
    float fxf = floorf(px), fyf = floorf(py), fzf = floorf(pz);
    float fx = px - fxf, fy = py - fyf, fz = pz - fzf;
    int lx = (int)fxf, ly = (int)fyf, lz = (int)fzf;
    int x0i = min(max(lx,0),127),   x1i = min(max(lx+1,0),127);
    int y0i = min(max(ly,0),127),   y1i = min(max(ly+1,0),127);
    int z0i = min(max(lz,0),127),   z1i = min(max(lz+1,0),127);
    float ex = 1.0f-fx, ey = 1.0f-fy, ez = 1.0f-fz;

    auto corner = [&](int xi,int yi,int zi,float w){
      const float4* p = reinterpret_cast<const float4*>(grid + ((size_t)((((xi<<7)+yi)<<7)+zi) << 3));
      float4 g0 = p[0]; float4 g1 = p[1];
      r0 = fmaf(g0.x, w, r0); r1 = fmaf(g0.y, w, r1); r2 = fmaf(g0.z, w, r2);
      r3 = fmaf(g0.w, w, r3); r4 = fmaf(g1.x, w, r4); r5 = fmaf(g1.y, w, r5);
      r6 = fmaf(g1.z, w, r6);
    };
    corner(x0i,y0i,z0i, ex*ey*ez);
    corner(x0i,y0i,z1i, ex*ey*fz);
    corner(x0i,y1i,z0i, ex*fy*ez);
    corner(x0i,y1i,z1i, ex*fy*fz);
    corner(x1i,y0i,z0i, fx*ey*ez);
    corner(x1i,y0i,z1i, fx*ey*fz);
    corner(x1i,y1i,z0i, fx*fy*ez);
    corner(x1i,y1i,z1i, fx*fy*fz);
  }

  float dmean = r3*0.125f;
  float denom = fmaxf(dmean, 1e-5f);
  float maskf = (dmean > 1e-5f) ? 1.0f : 0.0f;
  float fn0 = (r0*0.125f)/denom*maskf;
  float fn1 = (r1*0.125f)/denom*maskf;
  float fn2 = (r2*0.125f)/denom*maskf;
  float un0 = (r4*0.125f)/denom*maskf;
  float un1 = (r5*0.125f)/denom*maskf;
  float un2 = (r6*0.125f)/denom*maskf;

  // dec = [f_norm(3), u_norm(3), sin(pi x)(3), cos(pi x)(3), sin(2pi x)(3), cos(2pi x)(3), sin(4pi x)(3), cos(4pi x)(3)]
  float dec[24];
  dec[0]=fn0; dec[1]=fn1; dec[2]=fn2; dec[3]=un0; dec[4]=un1; dec[5]=un2;
  dec[6]  = __builtin_amdgcn_sinf(0.5f*qx01);  // v_sin takes revolutions: sin(2*pi*r)
  dec[7]  = __builtin_amdgcn_sinf(0.5f*qy01);
  dec[8]  = __builtin_amdgcn_sinf(0.5f*qz01);
  dec[9]  = __builtin_amdgcn_cosf(0.5f*qx01);
  dec[10] = __builtin_amdgcn_cosf(0.5f*qy01);
  dec[11] = __builtin_amdgcn_cosf(0.5f*qz01);
  dec[12] = __builtin_amdgcn_sinf(qx01);
  dec[13] = __builtin_amdgcn_sinf(qy01);
  dec[14] = __builtin_amdgcn_sinf(qz01);
  dec[15] = __builtin_amdgcn_cosf(qx01);
  dec[16] = __builtin_amdgcn_cosf(qy01);
  dec[17] = __builtin_amdgcn_cosf(qz01);
  dec[18] = __builtin_amdgcn_sinf(2.0f*qx01);
  dec[19] = __builtin_amdgcn_sinf(2.0f*qy01);
  dec[20] = __builtin_amdgcn_sinf(2.0f*qz01);
  dec[21] = __builtin_amdgcn_cosf(2.0f*qx01);
  dec[22] = __builtin_amdgcn_cosf(2.0f*qy01);
  dec[23] = __builtin_amdgcn_cosf(2.0f*qz01);

#pragma unroll
  for (int k2 = 0; k2 < 24; ++k2) row[k2] = dec[k2];

  // layer 1: 24 -> 64   (weights via wave-uniform scalar loads)
  float h[64];
#pragma unroll
  for (int j = 0; j < 64; ++j) h[j] = b1[j];
  for (int k2 = 0; k2 < 24; ++k2) {
    float dk = row[k2];
    const float* __restrict__ wr = W1 + (k2<<6);
#pragma unroll
    for (int j = 0; j < 64; ++j) h[j] = fmaf(dk, wr[j], h[j]);
  }

  // layer 2: 64 -> 64, h1 staged through LDS in two halves (keeps LDS at 8.4KB/block)
  float g2[64];
#pragma unroll
  for (int j = 0; j < 64; ++j) g2[j] = b2[j];
#pragma unroll
  for (int j = 0; j < 32; ++j) row[j] = gelu_f(h[j]);
  for (int k2 = 0; k2 < 32; ++k2) {
    float hk = row[k2];
    const float* __restrict__ wr = W2 + (k2<<6);
#pragma unroll
    for (int j = 0; j < 64; ++j) g2[j] = fmaf(hk, wr[j], g2[j]);
  }
#pragma unroll
  for (int j = 0; j < 32; ++j) row[j] = gelu_f(h[j+32]);
  for (int k2 = 0; k2 < 32; ++k2) {
    float hk = row[k2];
    const float* __restrict__ wr = W2 + ((k2+32)<<6);
#pragma unroll
    for (int j = 0; j < 64; ++j) g2[j] = fmaf(hk, wr[j], g2[j]);
  }

  // layer 3: 64 -> 3 (gelu applied to h2 first)
  float o0 = b3[0], o1 = b3[1], o2 = b3[2];
#pragma unroll
  for (int k2 = 0; k2 < 64; ++k2) {
    float g = gelu_f(g2[k2]);
    o0 = fmaf(g, W3[3*k2+0], o0);
    o1 = fmaf(g, W3[3*k2+1], o1);
    o2 = fmaf(g, W3[3*k2+2], o2);
  }

  out[3*m+0] = fminf(fmaxf(un0 + o0, 0.001f), 0.999f);
  out[3*m+1] = fminf(fmaxf(un1 + o1, 0.001f), 0.999f);
  out[3*m+2] = fminf(fmaxf(un2 + o2, 0.001f), 0.999f);
}

extern "C" void kernel_launch(void* const* d_in, const int* in_sizes, int n_in,
                              void* d_out, int out_size, void* d_ws, size_t ws_size,
                              hipStream_t stream)
{
  const float* xq  = (const float*)d_in[0];
  const float* xsr = (const float*)d_in[1];
  const float* xsc = (const float*)d_in[2];
  const float* Wf  = (const float*)d_in[3];
  const float* bf  = (const float*)d_in[4];
  const float* W1  = (const float*)d_in[5];
  const float* b1  = (const float*)d_in[6];
  const float* W2  = (const float*)d_in[7];
  const float* b2  = (const float*)d_in[8];
  const float* W3  = (const float*)d_in[9];
  const float* b3  = (const float*)d_in[10];
  float* out  = (float*)d_out;
  float* grid = (float*)d_ws;        // 128^3 cells x 8 floats (7 used + pad) = 64 MiB
  int M = in_sizes[0]/3;
  int N = in_sizes[1]/3;

  size_t gbytes = (size_t)(128*128*128) * 8 * sizeof(float);
  hipMemsetAsync(grid, 0, gbytes, stream);
  p2g_kernel<<<(N+255)/256, 256, 0, stream>>>(xsr, xsc, Wf, bf, grid, N);
  gather_mlp_kernel<<<(M+63)/64, 64, 0, stream>>>(xq, grid, W1, b1, W2, b2, W3, b3, out, M);
}

// Round 4
// 559.032 us; speedup vs baseline: 3.3160x; 3.3160x over previous
//
#include <hip/hip_runtime.h>
#include <cstdint>

#ifndef JAX_PARTITIONABLE
#define JAX_PARTITIONABLE 1   // modern JAX (>=0.5) default threefry_partitionable
#endif

#define NCELLS (128*128*128)          // 2,097,152
#define SCAN_BLOCKS 1024              // NCELLS / 2048

// ---------------- Threefry-2x32, key = (0, 42)  (jax.random.key(42)) ----------------
__device__ __forceinline__ uint32_t rotl32(uint32_t v, int s){ return (v << s) | (v >> (32 - s)); }

__device__ __forceinline__ void tf2x32(uint32_t& x0, uint32_t& x1){
  const uint32_t k0 = 0u, k1 = 42u;
  const uint32_t k2 = 0x1BD11BDAu ^ k0 ^ k1;
  x0 += k0; x1 += k1;
#define TFR(r) { x0 += x1; x1 = rotl32(x1,(r)); x1 ^= x0; }
  TFR(13) TFR(15) TFR(26) TFR(6)
  x0 += k1; x1 += k2 + 1u;
  TFR(17) TFR(29) TFR(16) TFR(24)
  x0 += k2; x1 += k0 + 2u;
  TFR(13) TFR(15) TFR(26) TFR(6)
  x0 += k0; x1 += k1 + 3u;
  TFR(17) TFR(29) TFR(16) TFR(24)
  x0 += k1; x1 += k2 + 4u;
  TFR(13) TFR(15) TFR(26) TFR(6)
  x0 += k2; x1 += k0 + 5u;
#undef TFR
}

// XLA f32 ErfInv (Giles) — exact coefficient match with jax/XLA
__device__ __forceinline__ float erfinv_xla(float x){
  float w = -log1pf(-x*x);
  float p;
  if (w < 5.0f){
    w -= 2.5f;
    p =  2.81022636e-08f;
    p = fmaf(p,w, 3.43273939e-07f);
    p = fmaf(p,w,-3.5233877e-06f);
    p = fmaf(p,w,-4.39150654e-06f);
    p = fmaf(p,w, 0.00021858087f);
    p = fmaf(p,w,-0.00125372503f);
    p = fmaf(p,w,-0.00417768164f);
    p = fmaf(p,w, 0.246640727f);
    p = fmaf(p,w, 1.50140941f);
  } else {
    w = sqrtf(w) - 3.0f;
    p = -0.000200214257f;
    p = fmaf(p,w, 0.000100950558f);
    p = fmaf(p,w, 0.00134934322f);
    p = fmaf(p,w,-0.00367342844f);
    p = fmaf(p,w, 0.00573950773f);
    p = fmaf(p,w,-0.0076224613f);
    p = fmaf(p,w, 0.00943887047f);
    p = fmaf(p,w, 1.00167406f);
    p = fmaf(p,w, 2.83297682f);
  }
  return p*x;
}

// noise[i] = 0.8 * sqrt(2)*erfinv(uniform(-1,1)) with jax bit semantics
__device__ __forceinline__ float noise_at(uint32_t idx, uint32_t half){
#if JAX_PARTITIONABLE
  (void)half;
  uint32_t x0 = 0u, x1 = idx;     // counter = (hi=0, lo=i)
  tf2x32(x0, x1);
  uint32_t bits = x0 ^ x1;        // partitionable 32-bit path: xor-fold of both words
#else
  uint32_t j  = (idx < half) ? idx : (idx - half);
  uint32_t x0 = j, x1 = j + half;
  tf2x32(x0, x1);
  uint32_t bits = (idx < half) ? x0 : x1;
#endif
  float f = __uint_as_float((bits >> 9) | 0x3f800000u) - 1.0f;      // [0,1)
  float u = fmaxf(-0.99999994f, fmaf(f, 2.0f, -0.99999994f));       // (-1,1)
  return (1.41421356f * erfinv_xla(u)) * 0.8f;
}

// jax.nn.gelu approximate=True
__device__ __forceinline__ float tanh_fast(float x){
  float e = __expf(2.0f * x);
  return 1.0f - 2.0f * __builtin_amdgcn_rcpf(e + 1.0f);
}
__device__ __forceinline__ float gelu_f(float x){
  float inner = 0.7978845608028654f * (x + 0.044715f*(x*x*x));
  return 0.5f * x * (1.0f + tanh_fast(inner));
}

// common per-particle geometry
__device__ __forceinline__ void particle_cell(const float* xsr, int i,
                                              float& sx, float& sy, float& sz,
                                              int& bx, int& by, int& bz,
                                              float& dx, float& dy, float& dz){
  sx = fminf(fmaxf(xsr[3*i+0], 0.0f), 1.0f);
  sy = fminf(fmaxf(xsr[3*i+1], 0.0f), 1.0f);
  sz = fminf(fmaxf(xsr[3*i+2], 0.0f), 1.0f);
  float cx = fminf(fmaxf(sx*127.0f, 0.0f), 126.999f);
  float cy = fminf(fmaxf(sy*127.0f, 0.0f), 126.999f);
  float cz = fminf(fmaxf(sz*127.0f, 0.0f), 126.999f);
  float bxf = floorf(cx), byf = floorf(cy), bzf = floorf(cz);
  bx = (int)bxf; by = (int)byf; bz = (int)bzf;
  dx = cx - bxf; dy = cy - byf; dz = cz - bzf;
}

// ---------------- binning pipeline ----------------
__global__ void __launch_bounds__(256) hist_kernel(const float* __restrict__ xsr,
                                                   int* __restrict__ cnt, int N){
  int i = blockIdx.x*256 + threadIdx.x;
  if (i >= N) return;
  float sx,sy,sz,dx,dy,dz; int bx,by,bz;
  particle_cell(xsr,i,sx,sy,sz,bx,by,bz,dx,dy,dz);
  int bin = (((bx<<7)+by)<<7)+bz;
  atomicAdd(&cnt[bin], 1);
}

// exclusive scan stage 1: 1024 blocks x 256 thr x 8 elems
__global__ void __launch_bounds__(256) scan1_kernel(const int* __restrict__ cnt,
                                                    int* __restrict__ offs,
                                                    int* __restrict__ bsum){
  __shared__ int lds[256];
  int t = threadIdx.x;
  int base = blockIdx.x*2048 + t*8;
  const int4* c4 = reinterpret_cast<const int4*>(cnt + base);
  int4 a0 = c4[0], a1 = c4[1];
  int s = a0.x+a0.y+a0.z+a0.w + a1.x+a1.y+a1.z+a1.w;
  lds[t] = s; __syncthreads();
  for (int off = 1; off < 256; off <<= 1){
    int v = (t >= off) ? lds[t-off] : 0;
    __syncthreads();
    lds[t] += v;
    __syncthreads();
  }
  int run = lds[t] - s;               // exclusive prefix of this thread's chunk
  if (t == 255) bsum[blockIdx.x] = lds[255];
  int* o = offs + base;
  o[0]=run; run+=a0.x; o[1]=run; run+=a0.y; o[2]=run; run+=a0.z; o[3]=run; run+=a0.w;
  o[4]=run; run+=a1.x; o[5]=run; run+=a1.y; o[6]=run; run+=a1.z; o[7]=run;
}

// stage 2: single block scans the 1024 block sums (exclusive), writes grand total at [1024]
__global__ void __launch_bounds__(1024) scan2_kernel(int* __restrict__ bsum){
  __shared__ int lds[1024];
  int t = threadIdx.x;
  int v = bsum[t];
  lds[t] = v; __syncthreads();
  for (int off = 1; off < 1024; off <<= 1){
    int u = (t >= off) ? lds[t-off] : 0;
    __syncthreads();
    lds[t] += u;
    __syncthreads();
  }
  bsum[t] = lds[t] - v;
  if (t == 1023) bsum[1024] = lds[1023];
}

// stage 3: add block offsets, init cursor, write sentinel
__global__ void __launch_bounds__(256) scan3_kernel(int* __restrict__ offs,
                                                    const int* __restrict__ bsum,
                                                    int* __restrict__ cursor){
  int i = blockIdx.x*256 + threadIdx.x;     // exactly NCELLS threads
  int o = offs[i] + bsum[i >> 11];
  offs[i] = o; cursor[i] = o;
  if (i == 0) offs[NCELLS] = bsum[SCAN_BLOCKS];
}

__global__ void __launch_bounds__(256) scatter_kernel(
    const float* __restrict__ xsr, const float* __restrict__ xsc,
    const float* __restrict__ Wf,  const float* __restrict__ bf,
    int* __restrict__ cursor,
    float4* __restrict__ pf, float4* __restrict__ pu, float* __restrict__ pz, int N){
  int i = blockIdx.x*256 + threadIdx.x;
  if (i >= N) return;
  float sx,sy,sz,dx,dy,dz; int bx,by,bz;
  particle_cell(xsr,i,sx,sy,sz,bx,by,bz,dx,dy,dz);
  float ux = xsc[3*i+0] - sx;
  float uy = xsc[3*i+1] - sy;
  float uz = xsc[3*i+2] - sz;
  float f0 = gelu_f(ux*Wf[0] + uy*Wf[3] + uz*Wf[6] + bf[0]);
  float f1 = gelu_f(ux*Wf[1] + uy*Wf[4] + uz*Wf[7] + bf[1]);
  float f2 = gelu_f(ux*Wf[2] + uy*Wf[5] + uz*Wf[8] + bf[2]);
  int bin = (((bx<<7)+by)<<7)+bz;
  int pos = atomicAdd(&cursor[bin], 1);
  pf[pos] = make_float4(f0, f1, f2, dx);
  pu[pos] = make_float4(ux, uy, uz, dy);
  pz[pos] = dz;
}

// per-cell gather: sums particles from the 8 neighbor bins; writes each cell once.
__global__ void __launch_bounds__(256) p2g_gather_kernel(
    const int* __restrict__ offs,
    const float4* __restrict__ pf, const float4* __restrict__ pu,
    const float* __restrict__ pz, float* __restrict__ grid){
  int cell = blockIdx.x*256 + threadIdx.x;   // exactly NCELLS threads
  int z = cell & 127, y = (cell >> 7) & 127, x = cell >> 14;
  float a0=0.f,a1=0.f,a2=0.f,a3=0.f,a4=0.f,a5=0.f,a6=0.f;
#pragma unroll
  for (int ox = 0; ox < 2; ++ox){
    int bx = x - ox; if ((unsigned)bx > 126u) continue;
#pragma unroll
    for (int oy = 0; oy < 2; ++oy){
      int by = y - oy; if ((unsigned)by > 126u) continue;
#pragma unroll
      for (int oz = 0; oz < 2; ++oz){
        int bz = z - oz; if ((unsigned)bz > 126u) continue;
        int bin = (((bx<<7)+by)<<7)+bz;
        int s = offs[bin], e = offs[bin+1];
        for (int p = s; p < e; ++p){
          float4 A = pf[p]; float4 B = pu[p]; float dz = pz[p];
          float wx = ox ? A.w : 1.0f - A.w;
          float wy = oy ? B.w : 1.0f - B.w;
          float wz = oz ? dz  : 1.0f - dz;
          float w = wx*wy*wz;
          a0 = fmaf(A.x,w,a0); a1 = fmaf(A.y,w,a1); a2 = fmaf(A.z,w,a2);
          a3 += w;
          a4 = fmaf(B.x,w,a4); a5 = fmaf(B.y,w,a5); a6 = fmaf(B.z,w,a6);
        }
      }
    }
  }
  float4* g = reinterpret_cast<float4*>(grid + ((size_t)cell << 3));
  g[0] = make_float4(a0,a1,a2,a3);
  g[1] = make_float4(a4,a5,a6,0.0f);
}

// ---------------- fallback: direct atomic P2G (used only if ws too small) ----------------
__global__ void __launch_bounds__(256) p2g_atomic_kernel(
    const float* __restrict__ xsr, const float* __restrict__ xsc,
    const float* __restrict__ Wf,  const float* __restrict__ bf,
    float* __restrict__ grid, int N)
{
  int i = blockIdx.x*256 + threadIdx.x;
  if (i >= N) return;
  float sx,sy,sz,dx,dy,dz; int bx,by,bz;
  particle_cell(xsr,i,sx,sy,sz,bx,by,bz,dx,dy,dz);
  float ux = xsc[3*i+0] - sx;
  float uy = xsc[3*i+1] - sy;
  float uz = xsc[3*i+2] - sz;
  float f0 = gelu_f(ux*Wf[0] + uy*Wf[3] + uz*Wf[6] + bf[0]);
  float f1 = gelu_f(ux*Wf[1] + uy*Wf[4] + uz*Wf[7] + bf[1]);
  float f2 = gelu_f(ux*Wf[2] + uy*Wf[5] + uz*Wf[8] + bf[2]);
  float ex = 1.0f - dx, ey = 1.0f - dy, ez = 1.0f - dz;
  auto splat = [&](int xi, int yi, int zi, float w){
    float* p = grid + ((size_t)((((xi<<7)+yi)<<7)+zi) << 3);
    unsafeAtomicAdd(p+0, f0*w);
    unsafeAtomicAdd(p+1, f1*w);
    unsafeAtomicAdd(p+2, f2*w);
    unsafeAtomicAdd(p+3, w);
    unsafeAtomicAdd(p+4, ux*w);
    unsafeAtomicAdd(p+5, uy*w);
    unsafeAtomicAdd(p+6, uz*w);
  };
  splat(bx,  by,  bz,   ex*ey*ez);
  splat(bx,  by,  bz+1, ex*ey*dz);
  splat(bx,  by+1,bz,   ex*dy*ez);
  splat(bx,  by+1,bz+1, ex*dy*dz);
  splat(bx+1,by,  bz,   dx*ey*ez);
  splat(bx+1,by,  bz+1, dx*ey*dz);
  splat(bx+1,by+1,bz,   dx*dy*ez);
  splat(bx+1,by+1,bz+1, dx*dy*dz);
}

// ---------------- gather (8 MC paths, trilerp) + normalize + posenc + MLP ----------------
__global__ void __launch_bounds__(64) gather_mlp_kernel(
    const float* __restrict__ xq,  const float* __restrict__ grid,
    const float* __restrict__ W1,  const float* __restrict__ b1,
    const float* __restrict__ W2,  const float* __restrict__ b2,
    const float* __restrict__ W3,  const float* __restrict__ b3,
    float* __restrict__ out, int M)
{
  __shared__ float sh[64*33];              // per-thread 33-float row; conflict-free
  int m = blockIdx.x*64 + threadIdx.x;
  if (m >= M) return;
  float* row = sh + threadIdx.x*33;

  float qx01 = fminf(fmaxf(xq[3*m+0], 0.0f), 1.0f);
  float qy01 = fminf(fmaxf(xq[3*m+1], 0.0f), 1.0f);
  float qz01 = fminf(fmaxf(xq[3*m+2], 0.0f), 1.0f);
  float qx = qx01*127.0f, qy = qy01*127.0f, qz = qz01*127.0f;

  float r0=0.f,r1=0.f,r2=0.f,r3=0.f,r4=0.f,r5=0.f,r6=0.f;
  const uint32_t KSTRIDE = 3u*(uint32_t)M;
  const uint32_t HALF    = 4u*KSTRIDE;
  uint32_t m3 = 3u*(uint32_t)m;

  for (int k = 0; k < 8; ++k) {
    uint32_t base = (uint32_t)k*KSTRIDE + m3;
    float px = qx + noise_at(base+0u, HALF);
    float py = qy + noise_at(base+1u, HALF);
    float pz = qz + noise_at(base+2u, HALF);
    float fxf = floorf(px), fyf = floorf(py), fzf = floorf(pz);
    float fx = px - fxf, fy = py - fyf, fz = pz - fzf;
    int lx = (int)fxf, ly = (int)fyf, lz = (int)fzf;
    int x0i = min(max(lx,0),127),   x1i = min(max(lx+1,0),127);
    int y0i = min(max(ly,0),127),   y1i = min(max(ly+1,0),127);
    int z0i = min(max(lz,0),127),   z1i = min(max(lz+1,0),127);
    float ex = 1.0f-fx, ey = 1.0f-fy, ez = 1.0f-fz;

    auto corner = [&](int xi,int yi,int zi,float w){
      const float4* p = reinterpret_cast<const float4*>(grid + ((size_t)((((xi<<7)+yi)<<7)+zi) << 3));
      float4 g0 = p[0]; float4 g1 = p[1];
      r0 = fmaf(g0.x, w, r0); r1 = fmaf(g0.y, w, r1); r2 = fmaf(g0.z, w, r2);
      r3 = fmaf(g0.w, w, r3); r4 = fmaf(g1.x, w, r4); r5 = fmaf(g1.y, w, r5);
      r6 = fmaf(g1.z, w, r6);
    };
    corner(x0i,y0i,z0i, ex*ey*ez);
    corner(x0i,y0i,z1i, ex*ey*fz);
    corner(x0i,y1i,z0i, ex*fy*ez);
    corner(x0i,y1i,z1i, ex*fy*fz);
    corner(x1i,y0i,z0i, fx*ey*ez);
    corner(x1i,y0i,z1i, fx*ey*fz);
    corner(x1i,y1i,z0i, fx*fy*ez);
    corner(x1i,y1i,z1i, fx*fy*fz);
  }

  float dmean = r3*0.125f;
  float denom = fmaxf(dmean, 1e-5f);
  float maskf = (dmean > 1e-5f) ? 1.0f : 0.0f;
  float fn0 = (r0*0.125f)/denom*maskf;
  float fn1 = (r1*0.125f)/denom*maskf;
  float fn2 = (r2*0.125f)/denom*maskf;
  float un0 = (r4*0.125f)/denom*maskf;
  float un1 = (r5*0.125f)/denom*maskf;
  float un2 = (r6*0.125f)/denom*maskf;

  float dec[24];
  dec[0]=fn0; dec[1]=fn1; dec[2]=fn2; dec[3]=un0; dec[4]=un1; dec[5]=un2;
  dec[6]  = __builtin_amdgcn_sinf(0.5f*qx01);
  dec[7]  = __builtin_amdgcn_sinf(0.5f*qy01);
  dec[8]  = __builtin_amdgcn_sinf(0.5f*qz01);
  dec[9]  = __builtin_amdgcn_cosf(0.5f*qx01);
  dec[10] = __builtin_amdgcn_cosf(0.5f*qy01);
  dec[11] = __builtin_amdgcn_cosf(0.5f*qz01);
  dec[12] = __builtin_amdgcn_sinf(qx01);
  dec[13] = __builtin_amdgcn_sinf(qy01);
  dec[14] = __builtin_amdgcn_sinf(qz01);
  dec[15] = __builtin_amdgcn_cosf(qx01);
  dec[16] = __builtin_amdgcn_cosf(qy01);
  dec[17] = __builtin_amdgcn_cosf(qz01);
  dec[18] = __builtin_amdgcn_sinf(2.0f*qx01);
  dec[19] = __builtin_amdgcn_sinf(2.0f*qy01);
  dec[20] = __builtin_amdgcn_sinf(2.0f*qz01);
  dec[21] = __builtin_amdgcn_cosf(2.0f*qx01);
  dec[22] = __builtin_amdgcn_cosf(2.0f*qy01);
  dec[23] = __builtin_amdgcn_cosf(2.0f*qz01);

#pragma unroll
  for (int k2 = 0; k2 < 24; ++k2) row[k2] = dec[k2];

  float h[64];
#pragma unroll
  for (int j = 0; j < 64; ++j) h[j] = b1[j];
  for (int k2 = 0; k2 < 24; ++k2) {
    float dk = row[k2];
    const float* __restrict__ wr = W1 + (k2<<6);
#pragma unroll
    for (int j = 0; j < 64; ++j) h[j] = fmaf(dk, wr[j], h[j]);
  }

  float g2[64];
#pragma unroll
  for (int j = 0; j < 64; ++j) g2[j] = b2[j];
#pragma unroll
  for (int j = 0; j < 32; ++j) row[j] = gelu_f(h[j]);
  for (int k2 = 0; k2 < 32; ++k2) {
    float hk = row[k2];
    const float* __restrict__ wr = W2 + (k2<<6);
#pragma unroll
    for (int j = 0; j < 64; ++j) g2[j] = fmaf(hk, wr[j], g2[j]);
  }
#pragma unroll
  for (int j = 0; j < 32; ++j) row[j] = gelu_f(h[j+32]);
  for (int k2 = 0; k2 < 32; ++k2) {
    float hk = row[k2];
    const float* __restrict__ wr = W2 + ((k2+32)<<6);
#pragma unroll
    for (int j = 0; j < 64; ++j) g2[j] = fmaf(hk, wr[j], g2[j]);
  }

  float o0 = b3[0], o1 = b3[1], o2 = b3[2];
#pragma unroll
  for (int k2 = 0; k2 < 64; ++k2) {
    float g = gelu_f(g2[k2]);
    o0 = fmaf(g, W3[3*k2+0], o0);
    o1 = fmaf(g, W3[3*k2+1], o1);
    o2 = fmaf(g, W3[3*k2+2], o2);
  }

  out[3*m+0] = fminf(fmaxf(un0 + o0, 0.001f), 0.999f);
  out[3*m+1] = fminf(fmaxf(un1 + o1, 0.001f), 0.999f);
  out[3*m+2] = fminf(fmaxf(un2 + o2, 0.001f), 0.999f);
}

extern "C" void kernel_launch(void* const* d_in, const int* in_sizes, int n_in,
                              void* d_out, int out_size, void* d_ws, size_t ws_size,
                              hipStream_t stream)
{
  const float* xq  = (const float*)d_in[0];
  const float* xsr = (const float*)d_in[1];
  const float* xsc = (const float*)d_in[2];
  const float* Wf  = (const float*)d_in[3];
  const float* bf  = (const float*)d_in[4];
  const float* W1  = (const float*)d_in[5];
  const float* b1  = (const float*)d_in[6];
  const float* W2  = (const float*)d_in[7];
  const float* b2  = (const float*)d_in[8];
  const float* W3  = (const float*)d_in[9];
  const float* b3  = (const float*)d_in[10];
  float* out  = (float*)d_out;
  int M = in_sizes[0]/3;
  int N = in_sizes[1]/3;

  // workspace layout (256B-aligned chunks)
  char* W = (char*)d_ws;
  size_t off = 0;
  auto alloc = [&](size_t bytes){ size_t o = off; off = (off + bytes + 255) & ~(size_t)255; return o; };
  size_t o_grid   = alloc((size_t)NCELLS * 8 * sizeof(float));   // 64 MiB
  size_t o_cnt    = alloc((size_t)NCELLS * sizeof(int));         // 8 MiB
  size_t o_offs   = alloc(((size_t)NCELLS + 1) * sizeof(int));   // 8 MiB
  size_t o_cursor = alloc((size_t)NCELLS * sizeof(int));         // 8 MiB
  size_t o_bsum   = alloc((size_t)(SCAN_BLOCKS + 1) * sizeof(int));
  size_t o_pf     = alloc((size_t)N * sizeof(float4));           // 8 MB
  size_t o_pu     = alloc((size_t)N * sizeof(float4));           // 8 MB
  size_t o_pz     = alloc((size_t)N * sizeof(float));            // 2 MB

  float*  grid   = (float*)(W + o_grid);
  int*    cnt    = (int*)(W + o_cnt);
  int*    offs   = (int*)(W + o_offs);
  int*    cursor = (int*)(W + o_cursor);
  int*    bsum   = (int*)(W + o_bsum);
  float4* pf     = (float4*)(W + o_pf);
  float4* pu     = (float4*)(W + o_pu);
  float*  pz     = (float*)(W + o_pz);

  if (off <= ws_size) {
    // binned gather path (no f32 atomics on the grid)
    hipMemsetAsync(cnt, 0, (size_t)NCELLS * sizeof(int), stream);
    hist_kernel<<<(N+255)/256, 256, 0, stream>>>(xsr, cnt, N);
    scan1_kernel<<<SCAN_BLOCKS, 256, 0, stream>>>(cnt, offs, bsum);
    scan2_kernel<<<1, 1024, 0, stream>>>(bsum);
    scan3_kernel<<<NCELLS/256, 256, 0, stream>>>(offs, bsum, cursor);
    scatter_kernel<<<(N+255)/256, 256, 0, stream>>>(xsr, xsc, Wf, bf, cursor, pf, pu, pz, N);
    p2g_gather_kernel<<<NCELLS/256, 256, 0, stream>>>(offs, pf, pu, pz, grid);
  } else {
    // fallback: direct atomic scatter
    hipMemsetAsync(grid, 0, (size_t)NCELLS * 8 * sizeof(float), stream);
    p2g_atomic_kernel<<<(N+255)/256, 256, 0, stream>>>(xsr, xsc, Wf, bf, grid, N);
  }
  gather_mlp_kernel<<<(M+63)/64, 64, 0, stream>>>(xq, grid, W1, b1, W2, b2, W3, b3, out, M);
}

// Round 5
// 452.872 us; speedup vs baseline: 4.0933x; 1.2344x over previous
//
#include <hip/hip_runtime.h>
#include <cstdint>

#ifndef JAX_PARTITIONABLE
#define JAX_PARTITIONABLE 1   // modern JAX (>=0.5) default threefry_partitionable
#endif

#define NCELLS (128*128*128)          // 2,097,152
#define SCAN_BLOCKS 1024              // NCELLS / 2048

// ---------------- Threefry-2x32, key = (0, 42)  (jax.random.key(42)) ----------------
__device__ __forceinline__ uint32_t rotl32(uint32_t v, int s){ return (v << s) | (v >> (32 - s)); }

__device__ __forceinline__ void tf2x32(uint32_t& x0, uint32_t& x1){
  const uint32_t k0 = 0u, k1 = 42u;
  const uint32_t k2 = 0x1BD11BDAu ^ k0 ^ k1;
  x0 += k0; x1 += k1;
#define TFR(r) { x0 += x1; x1 = rotl32(x1,(r)); x1 ^= x0; }
  TFR(13) TFR(15) TFR(26) TFR(6)
  x0 += k1; x1 += k2 + 1u;
  TFR(17) TFR(29) TFR(16) TFR(24)
  x0 += k2; x1 += k0 + 2u;
  TFR(13) TFR(15) TFR(26) TFR(6)
  x0 += k0; x1 += k1 + 3u;
  TFR(17) TFR(29) TFR(16) TFR(24)
  x0 += k1; x1 += k2 + 4u;
  TFR(13) TFR(15) TFR(26) TFR(6)
  x0 += k2; x1 += k0 + 5u;
#undef TFR
}

// XLA f32 ErfInv (Giles) — exact coefficient match with jax/XLA
__device__ __forceinline__ float erfinv_xla(float x){
  float w = -log1pf(-x*x);
  float p;
  if (w < 5.0f){
    w -= 2.5f;
    p =  2.81022636e-08f;
    p = fmaf(p,w, 3.43273939e-07f);
    p = fmaf(p,w,-3.5233877e-06f);
    p = fmaf(p,w,-4.39150654e-06f);
    p = fmaf(p,w, 0.00021858087f);
    p = fmaf(p,w,-0.00125372503f);
    p = fmaf(p,w,-0.00417768164f);
    p = fmaf(p,w, 0.246640727f);
    p = fmaf(p,w, 1.50140941f);
  } else {
    w = sqrtf(w) - 3.0f;
    p = -0.000200214257f;
    p = fmaf(p,w, 0.000100950558f);
    p = fmaf(p,w, 0.00134934322f);
    p = fmaf(p,w,-0.00367342844f);
    p = fmaf(p,w, 0.00573950773f);
    p = fmaf(p,w,-0.0076224613f);
    p = fmaf(p,w, 0.00943887047f);
    p = fmaf(p,w, 1.00167406f);
    p = fmaf(p,w, 2.83297682f);
  }
  return p*x;
}

// noise[i] = 0.8 * sqrt(2)*erfinv(uniform(-1,1)) with jax bit semantics
__device__ __forceinline__ float noise_at(uint32_t idx, uint32_t half){
#if JAX_PARTITIONABLE
  (void)half;
  uint32_t x0 = 0u, x1 = idx;     // counter = (hi=0, lo=i)
  tf2x32(x0, x1);
  uint32_t bits = x0 ^ x1;        // partitionable 32-bit path: xor-fold of both words
#else
  uint32_t j  = (idx < half) ? idx : (idx - half);
  uint32_t x0 = j, x1 = j + half;
  tf2x32(x0, x1);
  uint32_t bits = (idx < half) ? x0 : x1;
#endif
  float f = __uint_as_float((bits >> 9) | 0x3f800000u) - 1.0f;      // [0,1)
  float u = fmaxf(-0.99999994f, fmaf(f, 2.0f, -0.99999994f));       // (-1,1)
  return (1.41421356f * erfinv_xla(u)) * 0.8f;
}

// jax.nn.gelu approximate=True
__device__ __forceinline__ float tanh_fast(float x){
  float e = __expf(2.0f * x);
  return 1.0f - 2.0f * __builtin_amdgcn_rcpf(e + 1.0f);
}
__device__ __forceinline__ float gelu_f(float x){
  float inner = 0.7978845608028654f * (x + 0.044715f*(x*x*x));
  return 0.5f * x * (1.0f + tanh_fast(inner));
}

// common per-particle geometry
__device__ __forceinline__ void particle_cell(const float* xsr, int i,
                                              float& sx, float& sy, float& sz,
                                              int& bx, int& by, int& bz,
                                              float& dx, float& dy, float& dz){
  sx = fminf(fmaxf(xsr[3*i+0], 0.0f), 1.0f);
  sy = fminf(fmaxf(xsr[3*i+1], 0.0f), 1.0f);
  sz = fminf(fmaxf(xsr[3*i+2], 0.0f), 1.0f);
  float cx = fminf(fmaxf(sx*127.0f, 0.0f), 126.999f);
  float cy = fminf(fmaxf(sy*127.0f, 0.0f), 126.999f);
  float cz = fminf(fmaxf(sz*127.0f, 0.0f), 126.999f);
  float bxf = floorf(cx), byf = floorf(cy), bzf = floorf(cz);
  bx = (int)bxf; by = (int)byf; bz = (int)bzf;
  dx = cx - bxf; dy = cy - byf; dz = cz - bzf;
}

// ---------------- binning pipeline (shared by particles and queries) ----------------
__global__ void __launch_bounds__(256) hist_kernel(const float* __restrict__ xsr,
                                                   int* __restrict__ cnt, int N){
  int i = blockIdx.x*256 + threadIdx.x;
  if (i >= N) return;
  float sx,sy,sz,dx,dy,dz; int bx,by,bz;
  particle_cell(xsr,i,sx,sy,sz,bx,by,bz,dx,dy,dz);
  int bin = (((bx<<7)+by)<<7)+bz;
  atomicAdd(&cnt[bin], 1);
}

// exclusive scan stage 1: 1024 blocks x 256 thr x 8 elems
__global__ void __launch_bounds__(256) scan1_kernel(const int* __restrict__ cnt,
                                                    int* __restrict__ offs,
                                                    int* __restrict__ bsum){
  __shared__ int lds[256];
  int t = threadIdx.x;
  int base = blockIdx.x*2048 + t*8;
  const int4* c4 = reinterpret_cast<const int4*>(cnt + base);
  int4 a0 = c4[0], a1 = c4[1];
  int s = a0.x+a0.y+a0.z+a0.w + a1.x+a1.y+a1.z+a1.w;
  lds[t] = s; __syncthreads();
  for (int off = 1; off < 256; off <<= 1){
    int v = (t >= off) ? lds[t-off] : 0;
    __syncthreads();
    lds[t] += v;
    __syncthreads();
  }
  int run = lds[t] - s;               // exclusive prefix of this thread's chunk
  if (t == 255) bsum[blockIdx.x] = lds[255];
  int* o = offs + base;
  o[0]=run; run+=a0.x; o[1]=run; run+=a0.y; o[2]=run; run+=a0.z; o[3]=run; run+=a0.w;
  o[4]=run; run+=a1.x; o[5]=run; run+=a1.y; o[6]=run; run+=a1.z; o[7]=run;
}

// stage 2: single block scans the 1024 block sums (exclusive), writes grand total at [1024]
__global__ void __launch_bounds__(1024) scan2_kernel(int* __restrict__ bsum){
  __shared__ int lds[1024];
  int t = threadIdx.x;
  int v = bsum[t];
  lds[t] = v; __syncthreads();
  for (int off = 1; off < 1024; off <<= 1){
    int u = (t >= off) ? lds[t-off] : 0;
    __syncthreads();
    lds[t] += u;
    __syncthreads();
  }
  bsum[t] = lds[t] - v;
  if (t == 1023) bsum[1024] = lds[1023];
}

// stage 3: add block offsets, init cursor, write sentinel
__global__ void __launch_bounds__(256) scan3_kernel(int* __restrict__ offs,
                                                    const int* __restrict__ bsum,
                                                    int* __restrict__ cursor){
  int i = blockIdx.x*256 + threadIdx.x;     // exactly NCELLS threads
  int o = offs[i] + bsum[i >> 11];
  offs[i] = o; cursor[i] = o;
  if (i == 0) offs[NCELLS] = bsum[SCAN_BLOCKS];
}

__global__ void __launch_bounds__(256) scatter_kernel(
    const float* __restrict__ xsr, const float* __restrict__ xsc,
    const float* __restrict__ Wf,  const float* __restrict__ bf,
    int* __restrict__ cursor,
    float4* __restrict__ pf, float4* __restrict__ pu, float* __restrict__ pz, int N){
  int i = blockIdx.x*256 + threadIdx.x;
  if (i >= N) return;
  float sx,sy,sz,dx,dy,dz; int bx,by,bz;
  particle_cell(xsr,i,sx,sy,sz,bx,by,bz,dx,dy,dz);
  float ux = xsc[3*i+0] - sx;
  float uy = xsc[3*i+1] - sy;
  float uz = xsc[3*i+2] - sz;
  float f0 = gelu_f(ux*Wf[0] + uy*Wf[3] + uz*Wf[6] + bf[0]);
  float f1 = gelu_f(ux*Wf[1] + uy*Wf[4] + uz*Wf[7] + bf[1]);
  float f2 = gelu_f(ux*Wf[2] + uy*Wf[5] + uz*Wf[8] + bf[2]);
  int bin = (((bx<<7)+by)<<7)+bz;
  int pos = atomicAdd(&cursor[bin], 1);
  pf[pos] = make_float4(f0, f1, f2, dx);
  pu[pos] = make_float4(ux, uy, uz, dy);
  pz[pos] = dz;
}

// per-cell gather: sums particles from the 8 neighbor bins; writes each cell once.
__global__ void __launch_bounds__(256) p2g_gather_kernel(
    const int* __restrict__ offs,
    const float4* __restrict__ pf, const float4* __restrict__ pu,
    const float* __restrict__ pz, float* __restrict__ grid){
  int cell = blockIdx.x*256 + threadIdx.x;   // exactly NCELLS threads
  int z = cell & 127, y = (cell >> 7) & 127, x = cell >> 14;
  float a0=0.f,a1=0.f,a2=0.f,a3=0.f,a4=0.f,a5=0.f,a6=0.f;
#pragma unroll
  for (int ox = 0; ox < 2; ++ox){
    int bx = x - ox; if ((unsigned)bx > 126u) continue;
#pragma unroll
    for (int oy = 0; oy < 2; ++oy){
      int by = y - oy; if ((unsigned)by > 126u) continue;
#pragma unroll
      for (int oz = 0; oz < 2; ++oz){
        int bz = z - oz; if ((unsigned)bz > 126u) continue;
        int bin = (((bx<<7)+by)<<7)+bz;
        int s = offs[bin], e = offs[bin+1];
        for (int p = s; p < e; ++p){
          float4 A = pf[p]; float4 B = pu[p]; float dz = pz[p];
          float wx = ox ? A.w : 1.0f - A.w;
          float wy = oy ? B.w : 1.0f - B.w;
          float wz = oz ? dz  : 1.0f - dz;
          float w = wx*wy*wz;
          a0 = fmaf(A.x,w,a0); a1 = fmaf(A.y,w,a1); a2 = fmaf(A.z,w,a2);
          a3 += w;
          a4 = fmaf(B.x,w,a4); a5 = fmaf(B.y,w,a5); a6 = fmaf(B.z,w,a6);
        }
      }
    }
  }
  float4* g = reinterpret_cast<float4*>(grid + ((size_t)cell << 3));
  g[0] = make_float4(a0,a1,a2,a3);
  g[1] = make_float4(a4,a5,a6,0.0f);
}

// query binning: clip + bin by base cell (z-fastest key), stash clipped coords + index
__global__ void __launch_bounds__(256) qscatter_kernel(
    const float* __restrict__ xq, int* __restrict__ cursor,
    float* __restrict__ qs, int* __restrict__ qidx, int M){
  int i = blockIdx.x*256 + threadIdx.x;
  if (i >= M) return;
  float qx01 = fminf(fmaxf(xq[3*i+0], 0.0f), 1.0f);
  float qy01 = fminf(fmaxf(xq[3*i+1], 0.0f), 1.0f);
  float qz01 = fminf(fmaxf(xq[3*i+2], 0.0f), 1.0f);
  int bx = min((int)(qx01*127.0f), 127);
  int by = min((int)(qy01*127.0f), 127);
  int bz = min((int)(qz01*127.0f), 127);
  int bin = (((bx<<7)+by)<<7)+bz;
  int pos = atomicAdd(&cursor[bin], 1);
  qs[3*pos+0] = qx01; qs[3*pos+1] = qy01; qs[3*pos+2] = qz01;
  qidx[pos] = i;
}

__global__ void __launch_bounds__(256) qhist_kernel(const float* __restrict__ xq,
                                                    int* __restrict__ cnt, int M){
  int i = blockIdx.x*256 + threadIdx.x;
  if (i >= M) return;
  float qx01 = fminf(fmaxf(xq[3*i+0], 0.0f), 1.0f);
  float qy01 = fminf(fmaxf(xq[3*i+1], 0.0f), 1.0f);
  float qz01 = fminf(fmaxf(xq[3*i+2], 0.0f), 1.0f);
  int bx = min((int)(qx01*127.0f), 127);
  int by = min((int)(qy01*127.0f), 127);
  int bz = min((int)(qz01*127.0f), 127);
  atomicAdd(&cnt[(((bx<<7)+by)<<7)+bz], 1);
}

// ---------------- gather + MLP body (shared) ----------------
template<int BS>
__device__ __forceinline__ void gather_mlp_body(
    int m, float qx01, float qy01, float qz01, float* row,
    const float* __restrict__ grid,
    const float* __restrict__ W1,  const float* __restrict__ b1,
    const float* __restrict__ W2,  const float* __restrict__ b2,
    const float* __restrict__ W3,  const float* __restrict__ b3,
    float* __restrict__ out, int M)
{
  float qx = qx01*127.0f, qy = qy01*127.0f, qz = qz01*127.0f;

  float r0=0.f,r1=0.f,r2=0.f,r3=0.f,r4=0.f,r5=0.f,r6=0.f;
  const uint32_t KSTRIDE = 3u*(uint32_t)M;
  const uint32_t HALF    = 4u*KSTRIDE;
  uint32_t m3 = 3u*(uint32_t)m;

  for (int k = 0; k < 8; ++k) {
    uint32_t base = (uint32_t)k*KSTRIDE + m3;
    float px = qx + noise_at(base+0u, HALF);
    float py = qy + noise_at(base+1u, HALF);
    float pz = qz + noise_at(base+2u, HALF);
    float fxf = floorf(px), fyf = floorf(py), fzf = floorf(pz);
    float fx = px - fxf, fy = py - fyf, fz = pz - fzf;
    int lx = (int)fxf, ly = (int)fyf, lz = (int)fzf;
    int x0i = min(max(lx,0),127),   x1i = min(max(lx+1,0),127);
    int y0i = min(max(ly,0),127),   y1i = min(max(ly+1,0),127);
    int z0i = min(max(lz,0),127),   z1i = min(max(lz+1,0),127);
    float ex = 1.0f-fx, ey = 1.0f-fy, ez = 1.0f-fz;

    auto corner = [&](int xi,int yi,int zi,float w){
      const float4* p = reinterpret_cast<const float4*>(grid + ((size_t)((((xi<<7)+yi)<<7)+zi) << 3));
      float4 g0 = p[0]; float4 g1 = p[1];
      r0 = fmaf(g0.x, w, r0); r1 = fmaf(g0.y, w, r1); r2 = fmaf(g0.z, w, r2);
      r3 = fmaf(g0.w, w, r3); r4 = fmaf(g1.x, w, r4); r5 = fmaf(g1.y, w, r5);
      r6 = fmaf(g1.z, w, r6);
    };
    corner(x0i,y0i,z0i, ex*ey*ez);
    corner(x0i,y0i,z1i, ex*ey*fz);
    corner(x0i,y1i,z0i, ex*fy*ez);
    corner(x0i,y1i,z1i, ex*fy*fz);
    corner(x1i,y0i,z0i, fx*ey*ez);
    corner(x1i,y0i,z1i, fx*ey*fz);
    corner(x1i,y1i,z0i, fx*fy*ez);
    corner(x1i,y1i,z1i, fx*fy*fz);
  }

  float dmean = r3*0.125f;
  float denom = fmaxf(dmean, 1e-5f);
  float maskf = (dmean > 1e-5f) ? 1.0f : 0.0f;
  float fn0 = (r0*0.125f)/denom*maskf;
  float fn1 = (r1*0.125f)/denom*maskf;
  float fn2 = (r2*0.125f)/denom*maskf;
  float un0 = (r4*0.125f)/denom*maskf;
  float un1 = (r5*0.125f)/denom*maskf;
  float un2 = (r6*0.125f)/denom*maskf;

  float dec[24];
  dec[0]=fn0; dec[1]=fn1; dec[2]=fn2; dec[3]=un0; dec[4]=un1; dec[5]=un2;
  dec[6]  = __builtin_amdgcn_sinf(0.5f*qx01);   // v_sin input is revolutions
  dec[7]  = __builtin_amdgcn_sinf(0.5f*qy01);
  dec[8]  = __builtin_amdgcn_sinf(0.5f*qz01);
  dec[9]  = __builtin_amdgcn_cosf(0.5f*qx01);
  dec[10] = __builtin_amdgcn_cosf(0.5f*qy01);
  dec[11] = __builtin_amdgcn_cosf(0.5f*qz01);
  dec[12] = __builtin_amdgcn_sinf(qx01);
  dec[13] = __builtin_amdgcn_sinf(qy01);
  dec[14] = __builtin_amdgcn_sinf(qz01);
  dec[15] = __builtin_amdgcn_cosf(qx01);
  dec[16] = __builtin_amdgcn_cosf(qy01);
  dec[17] = __builtin_amdgcn_cosf(qz01);
  dec[18] = __builtin_amdgcn_sinf(2.0f*qx01);
  dec[19] = __builtin_amdgcn_sinf(2.0f*qy01);
  dec[20] = __builtin_amdgcn_sinf(2.0f*qz01);
  dec[21] = __builtin_amdgcn_cosf(2.0f*qx01);
  dec[22] = __builtin_amdgcn_cosf(2.0f*qy01);
  dec[23] = __builtin_amdgcn_cosf(2.0f*qz01);

#pragma unroll
  for (int k2 = 0; k2 < 24; ++k2) row[k2] = dec[k2];

  float h[64];
#pragma unroll
  for (int j = 0; j < 64; ++j) h[j] = b1[j];
  for (int k2 = 0; k2 < 24; ++k2) {
    float dk = row[k2];
    const float* __restrict__ wr = W1 + (k2<<6);
#pragma unroll
    for (int j = 0; j < 64; ++j) h[j] = fmaf(dk, wr[j], h[j]);
  }

  float g2[64];
#pragma unroll
  for (int j = 0; j < 64; ++j) g2[j] = b2[j];
#pragma unroll
  for (int j = 0; j < 32; ++j) row[j] = gelu_f(h[j]);
  for (int k2 = 0; k2 < 32; ++k2) {
    float hk = row[k2];
    const float* __restrict__ wr = W2 + (k2<<6);
#pragma unroll
    for (int j = 0; j < 64; ++j) g2[j] = fmaf(hk, wr[j], g2[j]);
  }
#pragma unroll
  for (int j = 0; j < 32; ++j) row[j] = gelu_f(h[j+32]);
  for (int k2 = 0; k2 < 32; ++k2) {
    float hk = row[k2];
    const float* __restrict__ wr = W2 + ((k2+32)<<6);
#pragma unroll
    for (int j = 0; j < 64; ++j) g2[j] = fmaf(hk, wr[j], g2[j]);
  }

  float o0 = b3[0], o1 = b3[1], o2 = b3[2];
#pragma unroll
  for (int k2 = 0; k2 < 64; ++k2) {
    float g = gelu_f(g2[k2]);
    o0 = fmaf(g, W3[3*k2+0], o0);
    o1 = fmaf(g, W3[3*k2+1], o1);
    o2 = fmaf(g, W3[3*k2+2], o2);
  }

  out[3*m+0] = fminf(fmaxf(un0 + o0, 0.001f), 0.999f);
  out[3*m+1] = fminf(fmaxf(un1 + o1, 0.001f), 0.999f);
  out[3*m+2] = fminf(fmaxf(un2 + o2, 0.001f), 0.999f);
}

// sorted-order gather: block b -> XCD-contiguous chunk of the spatially sorted queries
__global__ void __launch_bounds__(256) gather_mlp_sorted_kernel(
    const float* __restrict__ qs,  const int* __restrict__ qidx,
    const float* __restrict__ grid,
    const float* __restrict__ W1,  const float* __restrict__ b1,
    const float* __restrict__ W2,  const float* __restrict__ b2,
    const float* __restrict__ W3,  const float* __restrict__ b3,
    float* __restrict__ out, int M, int nblk)
{
  __shared__ float sh[256*33];
  int b = blockIdx.x;
  int nb8 = (nblk >> 3) << 3;
  int c = (b < nb8) ? ((b & 7)*(nblk >> 3) + (b >> 3)) : b;   // same-XCD blocks get contiguous chunks
  int t = c*256 + threadIdx.x;
  if (t >= M) return;
  float* row = sh + threadIdx.x*33;
  int m = qidx[t];
  gather_mlp_body<256>(m, qs[3*t+0], qs[3*t+1], qs[3*t+2], row,
                       grid, W1,b1,W2,b2,W3,b3, out, M);
}

// fallback: original-order gather (used only if ws too small for sorting buffers)
__global__ void __launch_bounds__(64) gather_mlp_kernel(
    const float* __restrict__ xq,  const float* __restrict__ grid,
    const float* __restrict__ W1,  const float* __restrict__ b1,
    const float* __restrict__ W2,  const float* __restrict__ b2,
    const float* __restrict__ W3,  const float* __restrict__ b3,
    float* __restrict__ out, int M)
{
  __shared__ float sh[64*33];
  int m = blockIdx.x*64 + threadIdx.x;
  if (m >= M) return;
  float* row = sh + threadIdx.x*33;
  float qx01 = fminf(fmaxf(xq[3*m+0], 0.0f), 1.0f);
  float qy01 = fminf(fmaxf(xq[3*m+1], 0.0f), 1.0f);
  float qz01 = fminf(fmaxf(xq[3*m+2], 0.0f), 1.0f);
  gather_mlp_body<64>(m, qx01, qy01, qz01, row, grid, W1,b1,W2,b2,W3,b3, out, M);
}

// ---------------- fallback: direct atomic P2G (used only if ws too small) ----------------
__global__ void __launch_bounds__(256) p2g_atomic_kernel(
    const float* __restrict__ xsr, const float* __restrict__ xsc,
    const float* __restrict__ Wf,  const float* __restrict__ bf,
    float* __restrict__ grid, int N)
{
  int i = blockIdx.x*256 + threadIdx.x;
  if (i >= N) return;
  float sx,sy,sz,dx,dy,dz; int bx,by,bz;
  particle_cell(xsr,i,sx,sy,sz,bx,by,bz,dx,dy,dz);
  float ux = xsc[3*i+0] - sx;
  float uy = xsc[3*i+1] - sy;
  float uz = xsc[3*i+2] - sz;
  float f0 = gelu_f(ux*Wf[0] + uy*Wf[3] + uz*Wf[6] + bf[0]);
  float f1 = gelu_f(ux*Wf[1] + uy*Wf[4] + uz*Wf[7] + bf[1]);
  float f2 = gelu_f(ux*Wf[2] + uy*Wf[5] + uz*Wf[8] + bf[2]);
  float ex = 1.0f - dx, ey = 1.0f - dy, ez = 1.0f - dz;
  auto splat = [&](int xi, int yi, int zi, float w){
    float* p = grid + ((size_t)((((xi<<7)+yi)<<7)+zi) << 3);
    unsafeAtomicAdd(p+0, f0*w);
    unsafeAtomicAdd(p+1, f1*w);
    unsafeAtomicAdd(p+2, f2*w);
    unsafeAtomicAdd(p+3, w);
    unsafeAtomicAdd(p+4, ux*w);
    unsafeAtomicAdd(p+5, uy*w);
    unsafeAtomicAdd(p+6, uz*w);
  };
  splat(bx,  by,  bz,   ex*ey*ez);
  splat(bx,  by,  bz+1, ex*ey*dz);
  splat(bx,  by+1,bz,   ex*dy*ez);
  splat(bx,  by+1,bz+1, ex*dy*dz);
  splat(bx+1,by,  bz,   dx*ey*ez);
  splat(bx+1,by,  bz+1, dx*ey*dz);
  splat(bx+1,by+1,bz,   dx*dy*ez);
  splat(bx+1,by+1,bz+1, dx*dy*dz);
}

extern "C" void kernel_launch(void* const* d_in, const int* in_sizes, int n_in,
                              void* d_out, int out_size, void* d_ws, size_t ws_size,
                              hipStream_t stream)
{
  const float* xq  = (const float*)d_in[0];
  const float* xsr = (const float*)d_in[1];
  const float* xsc = (const float*)d_in[2];
  const float* Wf  = (const float*)d_in[3];
  const float* bf  = (const float*)d_in[4];
  const float* W1  = (const float*)d_in[5];
  const float* b1  = (const float*)d_in[6];
  const float* W2  = (const float*)d_in[7];
  const float* b2  = (const float*)d_in[8];
  const float* W3  = (const float*)d_in[9];
  const float* b3  = (const float*)d_in[10];
  float* out  = (float*)d_out;
  int M = in_sizes[0]/3;
  int N = in_sizes[1]/3;

  // workspace layout (256B-aligned chunks)
  char* W = (char*)d_ws;
  size_t off = 0;
  auto alloc = [&](size_t bytes){ size_t o = off; off = (off + bytes + 255) & ~(size_t)255; return o; };
  size_t o_grid   = alloc((size_t)NCELLS * 8 * sizeof(float));   // 64 MiB
  size_t o_cnt    = alloc((size_t)NCELLS * sizeof(int));         // 8 MiB
  size_t o_offs   = alloc(((size_t)NCELLS + 1) * sizeof(int));   // 8 MiB
  size_t o_cursor = alloc((size_t)NCELLS * sizeof(int));         // 8 MiB
  size_t o_bsum   = alloc((size_t)(SCAN_BLOCKS + 1) * sizeof(int));
  size_t o_pf     = alloc((size_t)N * sizeof(float4));           // 8 MB
  size_t o_pu     = alloc((size_t)N * sizeof(float4));           // 8 MB
  size_t o_pz     = alloc((size_t)N * sizeof(float));            // 2 MB
  size_t binned_end = off;
  size_t o_qs     = alloc((size_t)M * 3 * sizeof(float));        // 6 MB
  size_t o_qidx   = alloc((size_t)M * sizeof(int));              // 2 MB
  size_t sorted_end = off;

  float*  grid   = (float*)(W + o_grid);
  int*    cnt    = (int*)(W + o_cnt);
  int*    offs   = (int*)(W + o_offs);
  int*    cursor = (int*)(W + o_cursor);
  int*    bsum   = (int*)(W + o_bsum);
  float4* pf     = (float4*)(W + o_pf);
  float4* pu     = (float4*)(W + o_pu);
  float*  pz     = (float*)(W + o_pz);
  float*  qs     = (float*)(W + o_qs);
  int*    qidx   = (int*)(W + o_qidx);

  if (binned_end <= ws_size) {
    // binned gather path (no f32 atomics on the grid)
    hipMemsetAsync(cnt, 0, (size_t)NCELLS * sizeof(int), stream);
    hist_kernel<<<(N+255)/256, 256, 0, stream>>>(xsr, cnt, N);
    scan1_kernel<<<SCAN_BLOCKS, 256, 0, stream>>>(cnt, offs, bsum);
    scan2_kernel<<<1, 1024, 0, stream>>>(bsum);
    scan3_kernel<<<NCELLS/256, 256, 0, stream>>>(offs, bsum, cursor);
    scatter_kernel<<<(N+255)/256, 256, 0, stream>>>(xsr, xsc, Wf, bf, cursor, pf, pu, pz, N);
    p2g_gather_kernel<<<NCELLS/256, 256, 0, stream>>>(offs, pf, pu, pz, grid);
  } else {
    hipMemsetAsync(grid, 0, (size_t)NCELLS * 8 * sizeof(float), stream);
    p2g_atomic_kernel<<<(N+255)/256, 256, 0, stream>>>(xsr, xsc, Wf, bf, grid, N);
  }

  if (sorted_end <= ws_size && binned_end <= ws_size) {
    // spatially sort queries (reusing cnt/offs/cursor/bsum after p2g_gather is done)
    hipMemsetAsync(cnt, 0, (size_t)NCELLS * sizeof(int), stream);
    qhist_kernel<<<(M+255)/256, 256, 0, stream>>>(xq, cnt, M);
    scan1_kernel<<<SCAN_BLOCKS, 256, 0, stream>>>(cnt, offs, bsum);
    scan2_kernel<<<1, 1024, 0, stream>>>(bsum);
    scan3_kernel<<<NCELLS/256, 256, 0, stream>>>(offs, bsum, cursor);
    qscatter_kernel<<<(M+255)/256, 256, 0, stream>>>(xq, cursor, qs, qidx, M);
    int nblk = (M + 255) / 256;
    gather_mlp_sorted_kernel<<<nblk, 256, 0, stream>>>(qs, qidx, grid, W1,b1,W2,b2,W3,b3, out, M, nblk);
  } else {
    gather_mlp_kernel<<<(M+63)/64, 64, 0, stream>>>(xq, grid, W1, b1, W2, b2, W3, b3, out, M);
  }
}

// Round 6
// 448.793 us; speedup vs baseline: 4.1305x; 1.0091x over previous
//
#include <hip/hip_runtime.h>
#include <cstdint>

#ifndef JAX_PARTITIONABLE
#define JAX_PARTITIONABLE 1   // modern JAX (>=0.5) default threefry_partitionable
#endif

#define NCELLS (128*128*128)          // 2,097,152
#define SCAN_BLOCKS 1024              // NCELLS / 2048
#define NQBINS (32*32*32)             // coarse query bins (4x4x4 cells each)

// ---------------- Threefry-2x32, key = (0, 42)  (jax.random.key(42)) ----------------
__device__ __forceinline__ uint32_t rotl32(uint32_t v, int s){ return (v << s) | (v >> (32 - s)); }

__device__ __forceinline__ void tf2x32(uint32_t& x0, uint32_t& x1){
  const uint32_t k0 = 0u, k1 = 42u;
  const uint32_t k2 = 0x1BD11BDAu ^ k0 ^ k1;
  x0 += k0; x1 += k1;
#define TFR(r) { x0 += x1; x1 = rotl32(x1,(r)); x1 ^= x0; }
  TFR(13) TFR(15) TFR(26) TFR(6)
  x0 += k1; x1 += k2 + 1u;
  TFR(17) TFR(29) TFR(16) TFR(24)
  x0 += k2; x1 += k0 + 2u;
  TFR(13) TFR(15) TFR(26) TFR(6)
  x0 += k0; x1 += k1 + 3u;
  TFR(17) TFR(29) TFR(16) TFR(24)
  x0 += k1; x1 += k2 + 4u;
  TFR(13) TFR(15) TFR(26) TFR(6)
  x0 += k2; x1 += k0 + 5u;
#undef TFR
}

// XLA f32 ErfInv (Giles) — exact coefficient match with jax/XLA
__device__ __forceinline__ float erfinv_xla(float x){
  float w = -log1pf(-x*x);
  float p;
  if (w < 5.0f){
    w -= 2.5f;
    p =  2.81022636e-08f;
    p = fmaf(p,w, 3.43273939e-07f);
    p = fmaf(p,w,-3.5233877e-06f);
    p = fmaf(p,w,-4.39150654e-06f);
    p = fmaf(p,w, 0.00021858087f);
    p = fmaf(p,w,-0.00125372503f);
    p = fmaf(p,w,-0.00417768164f);
    p = fmaf(p,w, 0.246640727f);
    p = fmaf(p,w, 1.50140941f);
  } else {
    w = sqrtf(w) - 3.0f;
    p = -0.000200214257f;
    p = fmaf(p,w, 0.000100950558f);
    p = fmaf(p,w, 0.00134934322f);
    p = fmaf(p,w,-0.00367342844f);
    p = fmaf(p,w, 0.00573950773f);
    p = fmaf(p,w,-0.0076224613f);
    p = fmaf(p,w, 0.00943887047f);
    p = fmaf(p,w, 1.00167406f);
    p = fmaf(p,w, 2.83297682f);
  }
  return p*x;
}

// noise[i] = 0.8 * sqrt(2)*erfinv(uniform(-1,1)) with jax bit semantics
__device__ __forceinline__ float noise_at(uint32_t idx, uint32_t half){
#if JAX_PARTITIONABLE
  (void)half;
  uint32_t x0 = 0u, x1 = idx;     // counter = (hi=0, lo=i)
  tf2x32(x0, x1);
  uint32_t bits = x0 ^ x1;        // partitionable 32-bit path: xor-fold of both words
#else
  uint32_t j  = (idx < half) ? idx : (idx - half);
  uint32_t x0 = j, x1 = j + half;
  tf2x32(x0, x1);
  uint32_t bits = (idx < half) ? x0 : x1;
#endif
  float f = __uint_as_float((bits >> 9) | 0x3f800000u) - 1.0f;      // [0,1)
  float u = fmaxf(-0.99999994f, fmaf(f, 2.0f, -0.99999994f));       // (-1,1)
  return (1.41421356f * erfinv_xla(u)) * 0.8f;
}

// jax.nn.gelu approximate=True
__device__ __forceinline__ float tanh_fast(float x){
  float e = __expf(2.0f * x);
  return 1.0f - 2.0f * __builtin_amdgcn_rcpf(e + 1.0f);
}
__device__ __forceinline__ float gelu_f(float x){
  float inner = 0.7978845608028654f * (x + 0.044715f*(x*x*x));
  return 0.5f * x * (1.0f + tanh_fast(inner));
}

// common per-particle geometry
__device__ __forceinline__ void particle_cell(const float* xsr, int i,
                                              float& sx, float& sy, float& sz,
                                              int& bx, int& by, int& bz,
                                              float& dx, float& dy, float& dz){
  sx = fminf(fmaxf(xsr[3*i+0], 0.0f), 1.0f);
  sy = fminf(fmaxf(xsr[3*i+1], 0.0f), 1.0f);
  sz = fminf(fmaxf(xsr[3*i+2], 0.0f), 1.0f);
  float cx = fminf(fmaxf(sx*127.0f, 0.0f), 126.999f);
  float cy = fminf(fmaxf(sy*127.0f, 0.0f), 126.999f);
  float cz = fminf(fmaxf(sz*127.0f, 0.0f), 126.999f);
  float bxf = floorf(cx), byf = floorf(cy), bzf = floorf(cz);
  bx = (int)bxf; by = (int)byf; bz = (int)bzf;
  dx = cx - bxf; dy = cy - byf; dz = cz - bzf;
}

// ---------------- particle binning pipeline ----------------
__global__ void __launch_bounds__(256) hist_kernel(const float* __restrict__ xsr,
                                                   int* __restrict__ cnt, int N){
  int i = blockIdx.x*256 + threadIdx.x;
  if (i >= N) return;
  float sx,sy,sz,dx,dy,dz; int bx,by,bz;
  particle_cell(xsr,i,sx,sy,sz,bx,by,bz,dx,dy,dz);
  int bin = (((bx<<7)+by)<<7)+bz;
  atomicAdd(&cnt[bin], 1);
}

// exclusive scan stage 1: 1024 blocks x 256 thr x 8 elems
__global__ void __launch_bounds__(256) scan1_kernel(const int* __restrict__ cnt,
                                                    int* __restrict__ offs,
                                                    int* __restrict__ bsum){
  __shared__ int lds[256];
  int t = threadIdx.x;
  int base = blockIdx.x*2048 + t*8;
  const int4* c4 = reinterpret_cast<const int4*>(cnt + base);
  int4 a0 = c4[0], a1 = c4[1];
  int s = a0.x+a0.y+a0.z+a0.w + a1.x+a1.y+a1.z+a1.w;
  lds[t] = s; __syncthreads();
  for (int off = 1; off < 256; off <<= 1){
    int v = (t >= off) ? lds[t-off] : 0;
    __syncthreads();
    lds[t] += v;
    __syncthreads();
  }
  int run = lds[t] - s;               // exclusive prefix of this thread's chunk
  if (t == 255) bsum[blockIdx.x] = lds[255];
  int* o = offs + base;
  o[0]=run; run+=a0.x; o[1]=run; run+=a0.y; o[2]=run; run+=a0.z; o[3]=run; run+=a0.w;
  o[4]=run; run+=a1.x; o[5]=run; run+=a1.y; o[6]=run; run+=a1.z; o[7]=run;
}

// stage 2: single block scans the 1024 block sums (exclusive), writes grand total at [1024]
__global__ void __launch_bounds__(1024) scan2_kernel(int* __restrict__ bsum){
  __shared__ int lds[1024];
  int t = threadIdx.x;
  int v = bsum[t];
  lds[t] = v; __syncthreads();
  for (int off = 1; off < 1024; off <<= 1){
    int u = (t >= off) ? lds[t-off] : 0;
    __syncthreads();
    lds[t] += u;
    __syncthreads();
  }
  bsum[t] = lds[t] - v;
  if (t == 1023) bsum[1024] = lds[1023];
}

// stage 3: add block offsets, init cursor, write sentinel
__global__ void __launch_bounds__(256) scan3_kernel(int* __restrict__ offs,
                                                    const int* __restrict__ bsum,
                                                    int* __restrict__ cursor){
  int i = blockIdx.x*256 + threadIdx.x;     // exactly NCELLS threads
  int o = offs[i] + bsum[i >> 11];
  offs[i] = o; cursor[i] = o;
  if (i == 0) offs[NCELLS] = bsum[SCAN_BLOCKS];
}

__global__ void __launch_bounds__(256) scatter_kernel(
    const float* __restrict__ xsr, const float* __restrict__ xsc,
    const float* __restrict__ Wf,  const float* __restrict__ bf,
    int* __restrict__ cursor,
    float4* __restrict__ pf, float4* __restrict__ pu, float* __restrict__ pz, int N){
  int i = blockIdx.x*256 + threadIdx.x;
  if (i >= N) return;
  float sx,sy,sz,dx,dy,dz; int bx,by,bz;
  particle_cell(xsr,i,sx,sy,sz,bx,by,bz,dx,dy,dz);
  float ux = xsc[3*i+0] - sx;
  float uy = xsc[3*i+1] - sy;
  float uz = xsc[3*i+2] - sz;
  float f0 = gelu_f(ux*Wf[0] + uy*Wf[3] + uz*Wf[6] + bf[0]);
  float f1 = gelu_f(ux*Wf[1] + uy*Wf[4] + uz*Wf[7] + bf[1]);
  float f2 = gelu_f(ux*Wf[2] + uy*Wf[5] + uz*Wf[8] + bf[2]);
  int bin = (((bx<<7)+by)<<7)+bz;
  int pos = atomicAdd(&cursor[bin], 1);
  pf[pos] = make_float4(f0, f1, f2, dx);
  pu[pos] = make_float4(ux, uy, uz, dy);
  pz[pos] = dz;
}

// per-cell gather: sums particles from the 8 neighbor bins; writes each cell once.
__global__ void __launch_bounds__(256) p2g_gather_kernel(
    const int* __restrict__ offs,
    const float4* __restrict__ pf, const float4* __restrict__ pu,
    const float* __restrict__ pz, float* __restrict__ grid){
  int cell = blockIdx.x*256 + threadIdx.x;   // exactly NCELLS threads
  int z = cell & 127, y = (cell >> 7) & 127, x = cell >> 14;
  float a0=0.f,a1=0.f,a2=0.f,a3=0.f,a4=0.f,a5=0.f,a6=0.f;
#pragma unroll
  for (int ox = 0; ox < 2; ++ox){
    int bx = x - ox; if ((unsigned)bx > 126u) continue;
#pragma unroll
    for (int oy = 0; oy < 2; ++oy){
      int by = y - oy; if ((unsigned)by > 126u) continue;
#pragma unroll
      for (int oz = 0; oz < 2; ++oz){
        int bz = z - oz; if ((unsigned)bz > 126u) continue;
        int bin = (((bx<<7)+by)<<7)+bz;
        int s = offs[bin], e = offs[bin+1];
        for (int p = s; p < e; ++p){
          float4 A = pf[p]; float4 B = pu[p]; float dz = pz[p];
          float wx = ox ? A.w : 1.0f - A.w;
          float wy = oy ? B.w : 1.0f - B.w;
          float wz = oz ? dz  : 1.0f - dz;
          float w = wx*wy*wz;
          a0 = fmaf(A.x,w,a0); a1 = fmaf(A.y,w,a1); a2 = fmaf(A.z,w,a2);
          a3 += w;
          a4 = fmaf(B.x,w,a4); a5 = fmaf(B.y,w,a5); a6 = fmaf(B.z,w,a6);
        }
      }
    }
  }
  float4* g = reinterpret_cast<float4*>(grid + ((size_t)cell << 3));
  g[0] = make_float4(a0,a1,a2,a3);
  g[1] = make_float4(a4,a5,a6,0.0f);
}

// ---------------- coarse query binning (32^3 bins of 4^3 cells) ----------------
__device__ __forceinline__ int qbin_of(float qx01, float qy01, float qz01){
  int bx = min((int)(qx01*127.0f), 127) >> 2;
  int by = min((int)(qy01*127.0f), 127) >> 2;
  int bz = min((int)(qz01*127.0f), 127) >> 2;
  return (((bx<<5)+by)<<5)+bz;
}

__global__ void __launch_bounds__(256) qhist_kernel(const float* __restrict__ xq,
                                                    int* __restrict__ cnt, int M){
  int i = blockIdx.x*256 + threadIdx.x;
  if (i >= M) return;
  float qx01 = fminf(fmaxf(xq[3*i+0], 0.0f), 1.0f);
  float qy01 = fminf(fmaxf(xq[3*i+1], 0.0f), 1.0f);
  float qz01 = fminf(fmaxf(xq[3*i+2], 0.0f), 1.0f);
  atomicAdd(&cnt[qbin_of(qx01,qy01,qz01)], 1);
}

// single-block exclusive scan over NQBINS counts -> offsets + cursor init
__global__ void __launch_bounds__(1024) qscan_kernel(const int* __restrict__ cnt,
                                                     int* __restrict__ cursor){
  __shared__ int lds[1024];
  int t = threadIdx.x;
  int base = t*32;
  int loc[32];
  int s = 0;
#pragma unroll
  for (int j = 0; j < 32; ++j){ loc[j] = cnt[base+j]; s += loc[j]; }
  lds[t] = s; __syncthreads();
  for (int off = 1; off < 1024; off <<= 1){
    int u = (t >= off) ? lds[t-off] : 0;
    __syncthreads();
    lds[t] += u;
    __syncthreads();
  }
  int run = lds[t] - s;
#pragma unroll
  for (int j = 0; j < 32; ++j){ cursor[base+j] = run; run += loc[j]; }
}

// query scatter: stash clipped coords + original index in coarse-sorted order
__global__ void __launch_bounds__(256) qscatter_kernel(
    const float* __restrict__ xq, int* __restrict__ cursor,
    float* __restrict__ qs, int* __restrict__ qidx, int M){
  int i = blockIdx.x*256 + threadIdx.x;
  if (i >= M) return;
  float qx01 = fminf(fmaxf(xq[3*i+0], 0.0f), 1.0f);
  float qy01 = fminf(fmaxf(xq[3*i+1], 0.0f), 1.0f);
  float qz01 = fminf(fmaxf(xq[3*i+2], 0.0f), 1.0f);
  int pos = atomicAdd(&cursor[qbin_of(qx01,qy01,qz01)], 1);
  qs[3*pos+0] = qx01; qs[3*pos+1] = qy01; qs[3*pos+2] = qz01;
  qidx[pos] = i;
}

// ---------------- gather + MLP body (shared) ----------------
__device__ __forceinline__ void gather_mlp_body(
    int m, float qx01, float qy01, float qz01, float* row,
    const float* __restrict__ grid,
    const float* __restrict__ W1,  const float* __restrict__ b1,
    const float* __restrict__ W2,  const float* __restrict__ b2,
    const float* __restrict__ W3,  const float* __restrict__ b3,
    float* __restrict__ out, int M)
{
  float qx = qx01*127.0f, qy = qy01*127.0f, qz = qz01*127.0f;

  float r0=0.f,r1=0.f,r2=0.f,r3=0.f,r4=0.f,r5=0.f,r6=0.f;
  const uint32_t KSTRIDE = 3u*(uint32_t)M;
  const uint32_t HALF    = 4u*KSTRIDE;
  uint32_t m3 = 3u*(uint32_t)m;

  for (int k = 0; k < 8; ++k) {
    uint32_t base = (uint32_t)k*KSTRIDE + m3;
    float px = qx + noise_at(base+0u, HALF);
    float py = qy + noise_at(base+1u, HALF);
    float pz = qz + noise_at(base+2u, HALF);
    float fxf = floorf(px), fyf = floorf(py), fzf = floorf(pz);
    float fx = px - fxf, fy = py - fyf, fz = pz - fzf;
    int lx = (int)fxf, ly = (int)fyf, lz = (int)fzf;
    int x0i = min(max(lx,0),127),   x1i = min(max(lx+1,0),127);
    int y0i = min(max(ly,0),127),   y1i = min(max(ly+1,0),127);
    int z0i = min(max(lz,0),127),   z1i = min(max(lz+1,0),127);
    float ex = 1.0f-fx, ey = 1.0f-fy, ez = 1.0f-fz;

    auto corner = [&](int xi,int yi,int zi,float w){
      const float4* p = reinterpret_cast<const float4*>(grid + ((size_t)((((xi<<7)+yi)<<7)+zi) << 3));
      float4 g0 = p[0]; float4 g1 = p[1];
      r0 = fmaf(g0.x, w, r0); r1 = fmaf(g0.y, w, r1); r2 = fmaf(g0.z, w, r2);
      r3 = fmaf(g0.w, w, r3); r4 = fmaf(g1.x, w, r4); r5 = fmaf(g1.y, w, r5);
      r6 = fmaf(g1.z, w, r6);
    };
    corner(x0i,y0i,z0i, ex*ey*ez);
    corner(x0i,y0i,z1i, ex*ey*fz);
    corner(x0i,y1i,z0i, ex*fy*ez);
    corner(x0i,y1i,z1i, ex*fy*fz);
    corner(x1i,y0i,z0i, fx*ey*ez);
    corner(x1i,y0i,z1i, fx*ey*fz);
    corner(x1i,y1i,z0i, fx*fy*ez);
    corner(x1i,y1i,z1i, fx*fy*fz);
  }

  float dmean = r3*0.125f;
  float denom = fmaxf(dmean, 1e-5f);
  float maskf = (dmean > 1e-5f) ? 1.0f : 0.0f;
  float fn0 = (r0*0.125f)/denom*maskf;
  float fn1 = (r1*0.125f)/denom*maskf;
  float fn2 = (r2*0.125f)/denom*maskf;
  float un0 = (r4*0.125f)/denom*maskf;
  float un1 = (r5*0.125f)/denom*maskf;
  float un2 = (r6*0.125f)/denom*maskf;

  float dec[24];
  dec[0]=fn0; dec[1]=fn1; dec[2]=fn2; dec[3]=un0; dec[4]=un1; dec[5]=un2;
  dec[6]  = __builtin_amdgcn_sinf(0.5f*qx01);   // v_sin input is revolutions
  dec[7]  = __builtin_amdgcn_sinf(0.5f*qy01);
  dec[8]  = __builtin_amdgcn_sinf(0.5f*qz01);
  dec[9]  = __builtin_amdgcn_cosf(0.5f*qx01);
  dec[10] = __builtin_amdgcn_cosf(0.5f*qy01);
  dec[11] = __builtin_amdgcn_cosf(0.5f*qz01);
  dec[12] = __builtin_amdgcn_sinf(qx01);
  dec[13] = __builtin_amdgcn_sinf(qy01);
  dec[14] = __builtin_amdgcn_sinf(qz01);
  dec[15] = __builtin_amdgcn_cosf(qx01);
  dec[16] = __builtin_amdgcn_cosf(qy01);
  dec[17] = __builtin_amdgcn_cosf(qz01);
  dec[18] = __builtin_amdgcn_sinf(2.0f*qx01);
  dec[19] = __builtin_amdgcn_sinf(2.0f*qy01);
  dec[20] = __builtin_amdgcn_sinf(2.0f*qz01);
  dec[21] = __builtin_amdgcn_cosf(2.0f*qx01);
  dec[22] = __builtin_amdgcn_cosf(2.0f*qy01);
  dec[23] = __builtin_amdgcn_cosf(2.0f*qz01);

#pragma unroll
  for (int k2 = 0; k2 < 24; ++k2) row[k2] = dec[k2];

  float h[64];
#pragma unroll
  for (int j = 0; j < 64; ++j) h[j] = b1[j];
  for (int k2 = 0; k2 < 24; ++k2) {
    float dk = row[k2];
    const float* __restrict__ wr = W1 + (k2<<6);
#pragma unroll
    for (int j = 0; j < 64; ++j) h[j] = fmaf(dk, wr[j], h[j]);
  }

  float g2[64];
#pragma unroll
  for (int j = 0; j < 64; ++j) g2[j] = b2[j];
#pragma unroll
  for (int j = 0; j < 32; ++j) row[j] = gelu_f(h[j]);
  for (int k2 = 0; k2 < 32; ++k2) {
    float hk = row[k2];
    const float* __restrict__ wr = W2 + (k2<<6);
#pragma unroll
    for (int j = 0; j < 64; ++j) g2[j] = fmaf(hk, wr[j], g2[j]);
  }
#pragma unroll
  for (int j = 0; j < 32; ++j) row[j] = gelu_f(h[j+32]);
  for (int k2 = 0; k2 < 32; ++k2) {
    float hk = row[k2];
    const float* __restrict__ wr = W2 + ((k2+32)<<6);
#pragma unroll
    for (int j = 0; j < 64; ++j) g2[j] = fmaf(hk, wr[j], g2[j]);
  }

  float o0 = b3[0], o1 = b3[1], o2 = b3[2];
#pragma unroll
  for (int k2 = 0; k2 < 64; ++k2) {
    float g = gelu_f(g2[k2]);
    o0 = fmaf(g, W3[3*k2+0], o0);
    o1 = fmaf(g, W3[3*k2+1], o1);
    o2 = fmaf(g, W3[3*k2+2], o2);
  }

  out[3*m+0] = fminf(fmaxf(un0 + o0, 0.001f), 0.999f);
  out[3*m+1] = fminf(fmaxf(un1 + o1, 0.001f), 0.999f);
  out[3*m+2] = fminf(fmaxf(un2 + o2, 0.001f), 0.999f);
}

// sorted-order gather: block b -> XCD-contiguous chunk of the spatially sorted queries
// __launch_bounds__(256,4): 4 waves/EU -> 128-VGPR budget; live set ~110 floats, no spill.
// LDS 33.8KB/block caps at 4 blocks/CU anyway, so the wider VGPR budget is free.
__global__ void __launch_bounds__(256, 4) gather_mlp_sorted_kernel(
    const float* __restrict__ qs,  const int* __restrict__ qidx,
    const float* __restrict__ grid,
    const float* __restrict__ W1,  const float* __restrict__ b1,
    const float* __restrict__ W2,  const float* __restrict__ b2,
    const float* __restrict__ W3,  const float* __restrict__ b3,
    float* __restrict__ out, int M, int nblk)
{
  __shared__ float sh[256*33];
  int b = blockIdx.x;
  int nb8 = (nblk >> 3) << 3;
  int c = (b < nb8) ? ((b & 7)*(nblk >> 3) + (b >> 3)) : b;   // same-XCD blocks get contiguous chunks
  int t = c*256 + threadIdx.x;
  if (t >= M) return;
  float* row = sh + threadIdx.x*33;
  int m = qidx[t];
  gather_mlp_body(m, qs[3*t+0], qs[3*t+1], qs[3*t+2], row,
                  grid, W1,b1,W2,b2,W3,b3, out, M);
}

// fallback: original-order gather (used only if ws too small for sorting buffers)
__global__ void __launch_bounds__(64, 4) gather_mlp_kernel(
    const float* __restrict__ xq,  const float* __restrict__ grid,
    const float* __restrict__ W1,  const float* __restrict__ b1,
    const float* __restrict__ W2,  const float* __restrict__ b2,
    const float* __restrict__ W3,  const float* __restrict__ b3,
    float* __restrict__ out, int M)
{
  __shared__ float sh[64*33];
  int m = blockIdx.x*64 + threadIdx.x;
  if (m >= M) return;
  float* row = sh + threadIdx.x*33;
  float qx01 = fminf(fmaxf(xq[3*m+0], 0.0f), 1.0f);
  float qy01 = fminf(fmaxf(xq[3*m+1], 0.0f), 1.0f);
  float qz01 = fminf(fmaxf(xq[3*m+2], 0.0f), 1.0f);
  gather_mlp_body(m, qx01, qy01, qz01, row, grid, W1,b1,W2,b2,W3,b3, out, M);
}

// ---------------- fallback: direct atomic P2G (used only if ws too small) ----------------
__global__ void __launch_bounds__(256) p2g_atomic_kernel(
    const float* __restrict__ xsr, const float* __restrict__ xsc,
    const float* __restrict__ Wf,  const float* __restrict__ bf,
    float* __restrict__ grid, int N)
{
  int i = blockIdx.x*256 + threadIdx.x;
  if (i >= N) return;
  float sx,sy,sz,dx,dy,dz; int bx,by,bz;
  particle_cell(xsr,i,sx,sy,sz,bx,by,bz,dx,dy,dz);
  float ux = xsc[3*i+0] - sx;
  float uy = xsc[3*i+1] - sy;
  float uz = xsc[3*i+2] - sz;
  float f0 = gelu_f(ux*Wf[0] + uy*Wf[3] + uz*Wf[6] + bf[0]);
  float f1 = gelu_f(ux*Wf[1] + uy*Wf[4] + uz*Wf[7] + bf[1]);
  float f2 = gelu_f(ux*Wf[2] + uy*Wf[5] + uz*Wf[8] + bf[2]);
  float ex = 1.0f - dx, ey = 1.0f - dy, ez = 1.0f - dz;
  auto splat = [&](int xi, int yi, int zi, float w){
    float* p = grid + ((size_t)((((xi<<7)+yi)<<7)+zi) << 3);
    unsafeAtomicAdd(p+0, f0*w);
    unsafeAtomicAdd(p+1, f1*w);
    unsafeAtomicAdd(p+2, f2*w);
    unsafeAtomicAdd(p+3, w);
    unsafeAtomicAdd(p+4, ux*w);
    unsafeAtomicAdd(p+5, uy*w);
    unsafeAtomicAdd(p+6, uz*w);
  };
  splat(bx,  by,  bz,   ex*ey*ez);
  splat(bx,  by,  bz+1, ex*ey*dz);
  splat(bx,  by+1,bz,   ex*dy*ez);
  splat(bx,  by+1,bz+1, ex*dy*dz);
  splat(bx+1,by,  bz,   dx*ey*ez);
  splat(bx+1,by,  bz+1, dx*ey*dz);
  splat(bx+1,by+1,bz,   dx*dy*ez);
  splat(bx+1,by+1,bz+1, dx*dy*dz);
}

extern "C" void kernel_launch(void* const* d_in, const int* in_sizes, int n_in,
                              void* d_out, int out_size, void* d_ws, size_t ws_size,
                              hipStream_t stream)
{
  const float* xq  = (const float*)d_in[0];
  const float* xsr = (const float*)d_in[1];
  const float* xsc = (const float*)d_in[2];
  const float* Wf  = (const float*)d_in[3];
  const float* bf  = (const float*)d_in[4];
  const float* W1  = (const float*)d_in[5];
  const float* b1  = (const float*)d_in[6];
  const float* W2  = (const float*)d_in[7];
  const float* b2  = (const float*)d_in[8];
  const float* W3  = (const float*)d_in[9];
  const float* b3  = (const float*)d_in[10];
  float* out  = (float*)d_out;
  int M = in_sizes[0]/3;
  int N = in_sizes[1]/3;

  // workspace layout (256B-aligned chunks)
  char* W = (char*)d_ws;
  size_t off = 0;
  auto alloc = [&](size_t bytes){ size_t o = off; off = (off + bytes + 255) & ~(size_t)255; return o; };
  size_t o_grid   = alloc((size_t)NCELLS * 8 * sizeof(float));   // 64 MiB
  size_t o_cnt    = alloc((size_t)NCELLS * sizeof(int));         // 8 MiB
  size_t o_offs   = alloc(((size_t)NCELLS + 1) * sizeof(int));   // 8 MiB
  size_t o_cursor = alloc((size_t)NCELLS * sizeof(int));         // 8 MiB
  size_t o_bsum   = alloc((size_t)(SCAN_BLOCKS + 1) * sizeof(int));
  size_t o_pf     = alloc((size_t)N * sizeof(float4));           // 8 MB
  size_t o_pu     = alloc((size_t)N * sizeof(float4));           // 8 MB
  size_t o_pz     = alloc((size_t)N * sizeof(float));            // 2 MB
  size_t binned_end = off;
  size_t o_qcnt   = alloc((size_t)NQBINS * sizeof(int));         // 128 KB
  size_t o_qcur   = alloc((size_t)NQBINS * sizeof(int));         // 128 KB
  size_t o_qs     = alloc((size_t)M * 3 * sizeof(float));        // 6 MB
  size_t o_qidx   = alloc((size_t)M * sizeof(int));              // 2 MB
  size_t sorted_end = off;

  float*  grid   = (float*)(W + o_grid);
  int*    cnt    = (int*)(W + o_cnt);
  int*    offs   = (int*)(W + o_offs);
  int*    cursor = (int*)(W + o_cursor);
  int*    bsum   = (int*)(W + o_bsum);
  float4* pf     = (float4*)(W + o_pf);
  float4* pu     = (float4*)(W + o_pu);
  float*  pz     = (float*)(W + o_pz);
  int*    qcnt   = (int*)(W + o_qcnt);
  int*    qcur   = (int*)(W + o_qcur);
  float*  qs     = (float*)(W + o_qs);
  int*    qidx   = (int*)(W + o_qidx);

  if (binned_end <= ws_size) {
    // binned gather path (no f32 atomics on the grid)
    hipMemsetAsync(cnt, 0, (size_t)NCELLS * sizeof(int), stream);
    hist_kernel<<<(N+255)/256, 256, 0, stream>>>(xsr, cnt, N);
    scan1_kernel<<<SCAN_BLOCKS, 256, 0, stream>>>(cnt, offs, bsum);
    scan2_kernel<<<1, 1024, 0, stream>>>(bsum);
    scan3_kernel<<<NCELLS/256, 256, 0, stream>>>(offs, bsum, cursor);
    scatter_kernel<<<(N+255)/256, 256, 0, stream>>>(xsr, xsc, Wf, bf, cursor, pf, pu, pz, N);
    p2g_gather_kernel<<<NCELLS/256, 256, 0, stream>>>(offs, pf, pu, pz, grid);
  } else {
    hipMemsetAsync(grid, 0, (size_t)NCELLS * 8 * sizeof(float), stream);
    p2g_atomic_kernel<<<(N+255)/256, 256, 0, stream>>>(xsr, xsc, Wf, bf, grid, N);
  }

  if (sorted_end <= ws_size) {
    // coarse spatial sort of queries (32^3 bins; runs concurrently-safe on stream)
    hipMemsetAsync(qcnt, 0, (size_t)NQBINS * sizeof(int), stream);
    qhist_kernel<<<(M+255)/256, 256, 0, stream>>>(xq, qcnt, M);
    qscan_kernel<<<1, 1024, 0, stream>>>(qcnt, qcur);
    qscatter_kernel<<<(M+255)/256, 256, 0, stream>>>(xq, qcur, qs, qidx, M);
    int nblk = (M + 255) / 256;
    gather_mlp_sorted_kernel<<<nblk, 256, 0, stream>>>(qs, qidx, grid, W1,b1,W2,b2,W3,b3, out, M, nblk);
  } else {
    gather_mlp_kernel<<<(M+63)/64, 64, 0, stream>>>(xq, grid, W1, b1, W2, b2, W3, b3, out, M);
  }
}